// Round 6
// baseline (115.167 us; speedup 1.0000x reference)
//
#include <hip/hip_runtime.h>
#include <math.h>

// ArcFace fused loss, B=512, C=100000, float32. Single fused kernel + 4B memset.
// loss_b = logsumexp_c(64*arcrow) - 64*theta_valid ; out = mean_b loss_b
// Fixed-shift logsumexp (|x|<1 -> 64x-64 in (-128,0), no overflow; underflow harmless).
// Label logit = dot(y_row, x_row) (y is exactly one-hot) -> side-effect-free hot loop.
// Cross-block: ticket zeroed each call via hipMemsetAsync (graph memset node);
// row_loss exchanged via agent-scope atomics (per-XCD L2s are not coherent --
// plain ld/st after threadfence can hit stale clean lines across graph replays).
// Winner block varies run-to-run but reduction order is fixed -> deterministic.

#define BB 512
#define CC 100000
#define C4 (CC / 4)           // 25000 float4 per row
#define BLK 1024
#define SWEEPS 6              // 6 * 4 * 1024 = 24576 float4
#define TAIL (C4 - SWEEPS * 4 * BLK)   // 424

// 64 * log2(e), for exp(64x-64) = exp2(K*x - K)
#define K64 92.33248261689366f

__device__ __forceinline__ float wave_reduce_add(float v) {
    #pragma unroll
    for (int off = 32; off > 0; off >>= 1)
        v += __shfl_down(v, off, 64);
    return v;
}

__device__ __forceinline__ float e64(float x) {
    return __builtin_amdgcn_exp2f(fmaf(K64, x, -K64));   // v_exp_f32
}

__global__ __launch_bounds__(BLK, 8) void arcface_fused(const float* __restrict__ y_true,
                                                        const float* __restrict__ logits,
                                                        float* __restrict__ row_loss,
                                                        unsigned int* __restrict__ ticket,
                                                        float* __restrict__ out) {
    const int row = blockIdx.x;
    const int tid = threadIdx.x;
    const float4* __restrict__ y4 = (const float4*)(y_true + (size_t)row * CC);
    const float4* __restrict__ x4 = (const float4*)(logits + (size_t)row * CC);

    __shared__ float s_sum[BLK / 64];
    __shared__ float s_dot[BLK / 64];
    __shared__ int s_last;

    float s0 = 0.0f, s1 = 0.0f;   // exp-sum accumulators (2 chains for ILP)
    float d0 = 0.0f, d1 = 0.0f;   // dot(y, x) accumulators
    int i = tid;

    #pragma unroll 1
    for (int k = 0; k < SWEEPS; ++k, i += 4 * BLK) {
        const float4 xa = x4[i];
        const float4 xb = x4[i + BLK];
        const float4 xc = x4[i + 2 * BLK];
        const float4 xd = x4[i + 3 * BLK];
        const float4 ya = y4[i];
        const float4 yb = y4[i + BLK];
        const float4 yc = y4[i + 2 * BLK];
        const float4 yd = y4[i + 3 * BLK];

        s0 += e64(xa.x); s1 += e64(xa.y); s0 += e64(xa.z); s1 += e64(xa.w);
        s0 += e64(xb.x); s1 += e64(xb.y); s0 += e64(xb.z); s1 += e64(xb.w);
        s0 += e64(xc.x); s1 += e64(xc.y); s0 += e64(xc.z); s1 += e64(xc.w);
        s0 += e64(xd.x); s1 += e64(xd.y); s0 += e64(xd.z); s1 += e64(xd.w);

        d0 = fmaf(ya.x, xa.x, d0); d1 = fmaf(ya.y, xa.y, d1);
        d0 = fmaf(ya.z, xa.z, d0); d1 = fmaf(ya.w, xa.w, d1);
        d0 = fmaf(yb.x, xb.x, d0); d1 = fmaf(yb.y, xb.y, d1);
        d0 = fmaf(yb.z, xb.z, d0); d1 = fmaf(yb.w, xb.w, d1);
        d0 = fmaf(yc.x, xc.x, d0); d1 = fmaf(yc.y, xc.y, d1);
        d0 = fmaf(yc.z, xc.z, d0); d1 = fmaf(yc.w, xc.w, d1);
        d0 = fmaf(yd.x, xd.x, d0); d1 = fmaf(yd.y, xd.y, d1);
        d0 = fmaf(yd.z, xd.z, d0); d1 = fmaf(yd.w, xd.w, d1);
    }

    // tail: 424 float4
    if (tid < TAIL) {
        const int j = SWEEPS * 4 * BLK + tid;
        const float4 y = y4[j];
        const float4 x = x4[j];
        s0 += e64(x.x); s1 += e64(x.y); s0 += e64(x.z); s1 += e64(x.w);
        d0 = fmaf(y.x, x.x, d0); d1 = fmaf(y.y, x.y, d1);
        d0 = fmaf(y.z, x.z, d0); d1 = fmaf(y.w, x.w, d1);
    }

    float s = wave_reduce_add(s0 + s1);
    float d = wave_reduce_add(d0 + d1);
    const int wid = tid >> 6;
    if ((tid & 63) == 0) { s_sum[wid] = s; s_dot[wid] = d; }
    __syncthreads();

    if (tid == 0) {
        float total = 0.0f, v = 0.0f;
        #pragma unroll
        for (int w = 0; w < BLK / 64; ++w) { total += s_sum[w]; v += s_dot[w]; }

        // margin1=1, margin2=0.5, margin3=0
        const float THRESH = -0.8775825618903728f;  // cos(pi - 0.5)
        const float theta = cosf(acosf(v) + 0.5f);
        const float tv = (v > THRESH) ? theta : (-2.0f - theta);

        // swap label term: remove exp(64v-64), add exp(64*tv-64)
        total += e64(tv) - e64(v);

        // loss_b = (64 + log(total)) - 64*tv
        const float loss = 64.0f + logf(total) - 64.0f * tv;

        // agent-scope release store (bypasses non-coherent per-XCD L2)
        __hip_atomic_store(&row_loss[row], loss, __ATOMIC_RELEASE,
                           __HIP_MEMORY_SCOPE_AGENT);
        const unsigned int old = __hip_atomic_fetch_add(ticket, 1u, __ATOMIC_ACQ_REL,
                                                        __HIP_MEMORY_SCOPE_AGENT);
        s_last = (old == (unsigned int)(BB - 1)) ? 1 : 0;
    }
    __syncthreads();

    if (s_last) {
        // last-arriving block: all 512 row_loss stores are globally visible
        float v2 = 0.0f;
        if (tid < BB)
            v2 = __hip_atomic_load(&row_loss[tid], __ATOMIC_ACQUIRE,
                                   __HIP_MEMORY_SCOPE_AGENT);
        v2 = wave_reduce_add(v2);
        if ((tid & 63) == 0) s_sum[wid] = v2;   // waves 8..15 contribute 0
        __syncthreads();
        if (tid == 0) {
            float t = 0.0f;
            #pragma unroll
            for (int w = 0; w < BLK / 64; ++w) t += s_sum[w];
            out[0] = t * (1.0f / (float)BB);
        }
    }
}

extern "C" void kernel_launch(void* const* d_in, const int* in_sizes, int n_in,
                              void* d_out, int out_size, void* d_ws, size_t ws_size,
                              hipStream_t stream) {
    const float* y_true = (const float*)d_in[0];
    const float* logits = (const float*)d_in[1];
    float* out = (float*)d_out;
    float* row_loss = (float*)d_ws;                       // 512 floats
    unsigned int* ticket = (unsigned int*)((char*)d_ws + BB * sizeof(float));

    hipMemsetAsync(ticket, 0, sizeof(unsigned int), stream);
    arcface_fused<<<BB, BLK, 0, stream>>>(y_true, logits, row_loss, ticket, out);
}

// Round 7
// 64.303 us; speedup vs baseline: 1.7910x; 1.7910x over previous
//
#include <hip/hip_runtime.h>
#include <math.h>

// ArcFace fused loss, B=512, C=100000, float32. Two kernels (fusion via
// device-scope atomics measured -35us — reverted).
// loss_b = logsumexp_c(64*arcrow) - 64*theta_valid ; out = mean_b loss_b
// Phase A: integer scan of one-hot y (nontemporal: keep y out of L3 so x stays
// resident). Phase B: pure exp2 sum over x. Label value via one scalar load,
// latency hidden under phase B.

#define BB 512
#define CC 100000
#define C4 (CC / 4)           // 25000 float4 per row
#define BLK 1024

// 64 * log2(e), for exp(64x-64) = exp2(K*x - K)
#define K64 92.33248261689366f

typedef unsigned int u32x4 __attribute__((ext_vector_type(4)));
typedef float f32x4 __attribute__((ext_vector_type(4)));

__device__ __forceinline__ float wave_reduce_add(float v) {
    #pragma unroll
    for (int off = 32; off > 0; off >>= 1)
        v += __shfl_down(v, off, 64);
    return v;
}

__device__ __forceinline__ float e64(float x) {
    return __builtin_amdgcn_exp2f(fmaf(K64, x, -K64));   // v_exp_f32
}

__global__ __launch_bounds__(BLK) void arcface_rows(const float* __restrict__ y_true,
                                                    const float* __restrict__ logits,
                                                    float* __restrict__ row_loss) {
    const int row = blockIdx.x;
    const int tid = threadIdx.x;
    const u32x4* __restrict__ y4 = (const u32x4*)(y_true + (size_t)row * CC);
    const f32x4* __restrict__ x4 = (const f32x4*)(logits + (size_t)row * CC);

    __shared__ int s_lab;
    __shared__ float s_sum[BLK / 64];

    // ---- phase A: find the one-hot index (integer compares, nontemporal) ----
    #pragma unroll 1
    for (int i = tid; i < C4; i += BLK) {
        const u32x4 u = __builtin_nontemporal_load(&y4[i]);
        if (u.x | u.y | u.z | u.w) {
            const int off = u.x ? 0 : (u.y ? 1 : (u.z ? 2 : 3));
            s_lab = 4 * i + off;   // exactly one finder in the block
        }
    }
    __syncthreads();

    // scalar load of the label logit; consumed only in the epilogue, so its
    // latency hides under all of phase B
    float val = 0.0f;
    if (tid == 0) val = logits[(size_t)row * CC + s_lab];

    // ---- phase B: exp-sum over x (pure stream, normal loads -> L3 resident) ----
    float s0 = 0.0f, s1 = 0.0f;
    #pragma unroll 1
    for (int i = tid; i < C4; i += BLK) {
        const f32x4 x = x4[i];
        s0 += e64(x.x); s1 += e64(x.y); s0 += e64(x.z); s1 += e64(x.w);
    }

    float s = wave_reduce_add(s0 + s1);
    if ((tid & 63) == 0) s_sum[tid >> 6] = s;
    __syncthreads();

    if (tid == 0) {
        float total = 0.0f;
        #pragma unroll
        for (int w = 0; w < BLK / 64; ++w) total += s_sum[w];

        // margin1=1, margin2=0.5, margin3=0
        const float THRESH = -0.8775825618903728f;  // cos(pi - 0.5)
        const float theta = cosf(acosf(val) + 0.5f);
        const float tv = (val > THRESH) ? theta : (-2.0f - theta);

        // swap label term: remove exp(64v-64), add exp(64*tv-64)
        total += e64(tv) - e64(val);

        // loss_b = (64 + log(total)) - 64*tv
        row_loss[row] = 64.0f + logf(total) - 64.0f * tv;
    }
}

__global__ __launch_bounds__(BB) void reduce_rows(const float* __restrict__ row_loss,
                                                  float* __restrict__ out) {
    const int tid = threadIdx.x;  // 512 threads
    float v = row_loss[tid];
    v = wave_reduce_add(v);
    __shared__ float s_wave[BB / 64];
    if ((tid & 63) == 0) s_wave[tid >> 6] = v;
    __syncthreads();
    if (tid == 0) {
        float t = 0.0f;
        #pragma unroll
        for (int w = 0; w < BB / 64; ++w) t += s_wave[w];
        out[0] = t * (1.0f / (float)BB);
    }
}

extern "C" void kernel_launch(void* const* d_in, const int* in_sizes, int n_in,
                              void* d_out, int out_size, void* d_ws, size_t ws_size,
                              hipStream_t stream) {
    const float* y_true = (const float*)d_in[0];
    const float* logits = (const float*)d_in[1];
    float* out = (float*)d_out;
    float* row_loss = (float*)d_ws;  // 512 floats

    arcface_rows<<<BB, BLK, 0, stream>>>(y_true, logits, row_loss);
    reduce_rows<<<1, BB, 0, stream>>>(row_loss, out);
}

// Round 8
// 55.529 us; speedup vs baseline: 2.0740x; 1.1580x over previous
//
#include <hip/hip_runtime.h>
#include <math.h>

// ArcFace fused loss, B=512, C=100000, float32.
// loss_b = logsumexp_c(64*arcrow) - 64*theta_valid ; out = mean_b loss_b
// Phase A: EARLY-EXIT integer scan of one-hot y (volatile LDS flag; expected
//   ~52% of y traffic since labels are uniform). Nontemporal loads keep y out
//   of L3 so x (200 MB < 256 MB L3) stays resident across graph replays.
// Phase B: pure exp2 sum over x.
// Mean fused via one device-scope atomicAdd per block into d_out, which is
// zeroed by a captured hipMemsetAsync node each call (no cross-replay
// accumulation). Order jitter ~1e-6 << 1.89 validation threshold.

#define BB 512
#define CC 100000
#define C4 (CC / 4)           // 25000 float4 per row
#define BLK 1024

// 64 * log2(e), for exp(64x-64) = exp2(K*x - K)
#define K64 92.33248261689366f

typedef unsigned int u32x4 __attribute__((ext_vector_type(4)));
typedef float f32x4 __attribute__((ext_vector_type(4)));

__device__ __forceinline__ float wave_reduce_add(float v) {
    #pragma unroll
    for (int off = 32; off > 0; off >>= 1)
        v += __shfl_down(v, off, 64);
    return v;
}

__device__ __forceinline__ float e64(float x) {
    return __builtin_amdgcn_exp2f(fmaf(K64, x, -K64));   // v_exp_f32
}

__global__ __launch_bounds__(BLK) void arcface_rows(const float* __restrict__ y_true,
                                                    const float* __restrict__ logits,
                                                    float* __restrict__ out) {
    const int row = blockIdx.x;
    const int tid = threadIdx.x;
    const u32x4* __restrict__ y4 = (const u32x4*)(y_true + (size_t)row * CC);
    const f32x4* __restrict__ x4 = (const f32x4*)(logits + (size_t)row * CC);

    __shared__ int s_lab;
    __shared__ float s_sum[BLK / 64];

    if (tid == 0) s_lab = -1;
    __syncthreads();
    volatile int* vlab = &s_lab;

    // ---- phase A: early-exit one-hot scan (integer compares, nontemporal) ----
    #pragma unroll 1
    for (int i = tid; i < C4; i += BLK) {
        if (*vlab >= 0) break;             // another lane already found it
        const u32x4 u = __builtin_nontemporal_load(&y4[i]);
        if (u.x | u.y | u.z | u.w) {
            const int off = u.x ? 0 : (u.y ? 1 : (u.z ? 2 : 3));
            *vlab = 4 * i + off;           // exactly one finder per row
        }
    }
    __syncthreads();
    const int lab = s_lab;

    // scalar load of the label logit; consumed only in the epilogue, so its
    // latency hides under all of phase B
    float val = 0.0f;
    if (tid == 0) val = logits[(size_t)row * CC + lab];

    // ---- phase B: exp-sum over x (pure stream, normal loads -> L3 resident) ----
    float s0 = 0.0f, s1 = 0.0f;
    #pragma unroll 1
    for (int i = tid; i < C4; i += BLK) {
        const f32x4 x = x4[i];
        s0 += e64(x.x); s1 += e64(x.y); s0 += e64(x.z); s1 += e64(x.w);
    }

    float s = wave_reduce_add(s0 + s1);
    if ((tid & 63) == 0) s_sum[tid >> 6] = s;
    __syncthreads();

    if (tid == 0) {
        float total = 0.0f;
        #pragma unroll
        for (int w = 0; w < BLK / 64; ++w) total += s_sum[w];

        // margin1=1, margin2=0.5, margin3=0
        const float THRESH = -0.8775825618903728f;  // cos(pi - 0.5)
        const float theta = cosf(acosf(val) + 0.5f);
        const float tv = (val > THRESH) ? theta : (-2.0f - theta);

        // swap label term: remove exp(64v-64), add exp(64*tv-64)
        total += e64(tv) - e64(val);

        // loss_b = (64 + log(total)) - 64*tv ; contribute loss_b/B to the mean
        const float loss = 64.0f + logf(total) - 64.0f * tv;
        atomicAdd(out, loss * (1.0f / (float)BB));   // device-scope by default
    }
}

extern "C" void kernel_launch(void* const* d_in, const int* in_sizes, int n_in,
                              void* d_out, int out_size, void* d_ws, size_t ws_size,
                              hipStream_t stream) {
    const float* y_true = (const float*)d_in[0];
    const float* logits = (const float*)d_in[1];
    float* out = (float*)d_out;

    hipMemsetAsync(out, 0, sizeof(float), stream);   // graph memset node
    arcface_rows<<<BB, BLK, 0, stream>>>(y_true, logits, out);
}